// Round 10
// baseline (19.429 us; speedup 1.0000x reference)
//
#include <hip/hip_runtime.h>

#define BLOCK 256
#define COLS 8              // output columns (true boxes) per block
#define WAVES (BLOCK / 64)

__global__ __launch_bounds__(BLOCK) void iou_onepass(
    const float* __restrict__ pred,   // [N,4] raw
    const float* __restrict__ trub,   // [M,4] raw
    float* __restrict__ out,          // [M] loss, fully written each call
    int N, int M)
{
    __shared__ float swv[WAVES][COLS];
    __shared__ int   sbad[WAVES];

    const int tid  = threadIdx.x;
    const int lane = tid & 63;
    const int wv   = tid >> 6;
    const int jb   = blockIdx.x * COLS;

    // ---- uniform true boxes for this block (scalarized loads, SGPR-resident) ----
    float tx[COLS], ty[COLS], gx2[COLS], gy2[COLS], ga[COLS];
    bool bad = false;
#pragma unroll
    for (int c = 0; c < COLS; ++c) {
        int j = jb + c; if (j >= M) j = M - 1;      // clamp: duplicate, write-guarded later
        float4 b = reinterpret_cast<const float4*>(trub)[j];
        float x1 = fminf(b.x, b.z), y1 = fminf(b.y, b.w);
        float x2 = fmaxf(b.x, b.z), y2 = fmaxf(b.y, b.w);
        bad = bad || (x2 > x1 + 1.0f) || (y2 > y1 + 1.0f);   // unit-box check (EPS=1)
        x2 = fmaxf(x2, x1 + 1.0f); y2 = fmaxf(y2, y1 + 1.0f);
        tx[c] = x1; ty[c] = y1; gx2[c] = x2; gy2[c] = y2;
        ga[c] = (x2 - x1) * (y2 - y1);
    }

    float best[COLS];
#pragma unroll
    for (int c = 0; c < COLS; ++c) best[c] = 0.0f;

    // ---- fast scan: all boxes assumed 1x1; track max INTERSECTION + badness ----
#pragma unroll 4
    for (int i = tid; i < N; i += BLOCK) {
        float4 b = reinterpret_cast<const float4*>(pred)[i];
        float x1 = fminf(b.x, b.z), y1 = fminf(b.y, b.w);
        float x2 = fmaxf(b.x, b.z), y2 = fmaxf(b.y, b.w);
        bad = bad || (x2 > x1 + 1.0f) || (y2 > y1 + 1.0f);
#pragma unroll
        for (int c = 0; c < COLS; ++c) {
            float wx = 1.0f - fabsf(x1 - tx[c]);               // may be < 0
            float hy = fmaxf(1.0f - fabsf(y1 - ty[c]), 0.0f);  // clamped
            best[c] = fmaxf(best[c], wx * hy);  // wx<0 => product<=0, discarded
        }
    }

    // ---- block vote on fast-path validity ----
    int ab = __any(bad) ? 1 : 0;
    if (lane == 0) sbad[wv] = ab;
    __syncthreads();
    int blkbad = 0;
#pragma unroll
    for (int w = 0; w < WAVES; ++w) blkbad |= sbad[w];

    if (blkbad) {
        // ---- generic rescan (rare): full IoU, preds L2-warm ----
#pragma unroll
        for (int c = 0; c < COLS; ++c) best[c] = 0.0f;
        for (int i = tid; i < N; i += BLOCK) {
            float4 b = reinterpret_cast<const float4*>(pred)[i];
            float x1 = fminf(b.x, b.z), y1 = fminf(b.y, b.w);
            float x2 = fmaxf(b.x, b.z), y2 = fmaxf(b.y, b.w);
            x2 = fmaxf(x2, x1 + 1.0f); y2 = fmaxf(y2, y1 + 1.0f);
            float pa = (x2 - x1) * (y2 - y1);
#pragma unroll
            for (int c = 0; c < COLS; ++c) {
                float lx = fmaxf(x1, tx[c]);
                float ly = fmaxf(y1, ty[c]);
                float rx = fminf(x2, gx2[c]);
                float ry = fminf(y2, gy2[c]);
                float w  = fmaxf(rx - lx, 0.0f);
                float h  = fmaxf(ry - ly, 0.0f);
                float inter = w * h;
                float uni   = (pa + ga[c]) - inter;   // >= 1 (EPS forces dims >= 1)
                best[c] = fmaxf(best[c], inter * __builtin_amdgcn_rcpf(uni));
            }
        }
    } else {
        // intersection -> IoU: i/(2-i), monotone, 2-i in [1,2]
#pragma unroll
        for (int c = 0; c < COLS; ++c)
            best[c] = best[c] * __builtin_amdgcn_rcpf(2.0f - best[c]);
    }

    // ---- wave shuffle max-reduce, then cross-wave LDS combine ----
#pragma unroll
    for (int c = 0; c < COLS; ++c) {
#pragma unroll
        for (int off = 32; off >= 1; off >>= 1)
            best[c] = fmaxf(best[c], __shfl_xor(best[c], off, 64));
    }
    if (lane == 0) {
#pragma unroll
        for (int c = 0; c < COLS; ++c) swv[wv][c] = best[c];
    }
    __syncthreads();
    if (tid < COLS) {
        float m = swv[0][tid];
#pragma unroll
        for (int w = 1; w < WAVES; ++w) m = fmaxf(m, swv[w][tid]);
        int j = jb + tid;
        if (j < M) out[j] = 1.0f - m;
    }
}

extern "C" void kernel_launch(void* const* d_in, const int* in_sizes, int n_in,
                              void* d_out, int out_size, void* d_ws, size_t ws_size,
                              hipStream_t stream) {
    const float* pred = (const float*)d_in[0];
    const float* trub = (const float*)d_in[1];
    float* out = (float*)d_out;
    const int N = in_sizes[0] / 4;
    const int M = in_sizes[1] / 4;

    // one node: each block owns COLS disjoint outputs, scans all preds (L2-resident)
    int nblk = (M + COLS - 1) / COLS;   // 1024 for M=8192
    iou_onepass<<<nblk, BLOCK, 0, stream>>>(pred, trub, out, N, M);
}

// Round 11
// 18.687 us; speedup vs baseline: 1.0397x; 1.0397x over previous
//
#include <hip/hip_runtime.h>

#define BLOCK 256
#define COLS 16             // output columns (true boxes) per block
#define WAVES (BLOCK / 64)

__global__ __launch_bounds__(BLOCK) void iou_onepass(
    const float* __restrict__ pred,   // [N,4] raw
    const float* __restrict__ trub,   // [M,4] raw
    float* __restrict__ out,          // [M] loss, fully written each call
    int N, int M)
{
    __shared__ float swv[WAVES][COLS];
    __shared__ int   sbad[WAVES];

    const int tid  = threadIdx.x;
    const int lane = tid & 63;
    const int wv   = tid >> 6;
    const int jb   = blockIdx.x * COLS;

    // ---- uniform true-box corners for this block (block-uniform -> scalarized) ----
    float tx[COLS], ty[COLS];
    bool bad = false;
#pragma unroll
    for (int c = 0; c < COLS; ++c) {
        int j = jb + c; if (j >= M) j = M - 1;      // clamp: duplicate, write-guarded later
        float4 b = reinterpret_cast<const float4*>(trub)[j];
        float x1 = fminf(b.x, b.z), y1 = fminf(b.y, b.w);
        float x2 = fmaxf(b.x, b.z), y2 = fmaxf(b.y, b.w);
        bad = bad || (x2 > x1 + 1.0f) || (y2 > y1 + 1.0f);   // unit-box check (EPS=1)
        tx[c] = x1; ty[c] = y1;
    }

    float best[COLS];
#pragma unroll
    for (int c = 0; c < COLS; ++c) best[c] = 0.0f;

    // ---- fast scan: assume 1x1 boxes; track max INTERSECTION + badness ----
#pragma unroll 4
    for (int i = tid; i < N; i += BLOCK) {
        float4 b = reinterpret_cast<const float4*>(pred)[i];
        float x1 = fminf(b.x, b.z), y1 = fminf(b.y, b.w);
        float x2 = fmaxf(b.x, b.z), y2 = fmaxf(b.y, b.w);
        bad = bad || (x2 > x1 + 1.0f) || (y2 > y1 + 1.0f);
#pragma unroll
        for (int c = 0; c < COLS; ++c) {
            float wx = 1.0f - fabsf(x1 - tx[c]);               // may be < 0
            float hy = fmaxf(1.0f - fabsf(y1 - ty[c]), 0.0f);  // clamped
            best[c] = fmaxf(best[c], wx * hy);  // wx<0 => product<=0, discarded
        }
    }

    // ---- block vote on fast-path validity ----
    int ab = __any(bad) ? 1 : 0;
    if (lane == 0) sbad[wv] = ab;
    __syncthreads();
    int blkbad = 0;
#pragma unroll
    for (int w = 0; w < WAVES; ++w) blkbad |= sbad[w];

    if (blkbad) {
        // ---- generic rescan (never taken for unit-box data): full IoU ----
        float gx1[COLS], gy1[COLS], gx2[COLS], gy2[COLS], ga[COLS];
#pragma unroll
        for (int c = 0; c < COLS; ++c) {
            int j = jb + c; if (j >= M) j = M - 1;
            float4 b = reinterpret_cast<const float4*>(trub)[j];
            float x1 = fminf(b.x, b.z), y1 = fminf(b.y, b.w);
            float x2 = fmaxf(b.x, b.z), y2 = fmaxf(b.y, b.w);
            x2 = fmaxf(x2, x1 + 1.0f); y2 = fmaxf(y2, y1 + 1.0f);
            gx1[c] = x1; gy1[c] = y1; gx2[c] = x2; gy2[c] = y2;
            ga[c] = (x2 - x1) * (y2 - y1);
            best[c] = 0.0f;
        }
        for (int i = tid; i < N; i += BLOCK) {
            float4 b = reinterpret_cast<const float4*>(pred)[i];
            float x1 = fminf(b.x, b.z), y1 = fminf(b.y, b.w);
            float x2 = fmaxf(b.x, b.z), y2 = fmaxf(b.y, b.w);
            x2 = fmaxf(x2, x1 + 1.0f); y2 = fmaxf(y2, y1 + 1.0f);
            float pa = (x2 - x1) * (y2 - y1);
#pragma unroll
            for (int c = 0; c < COLS; ++c) {
                float lx = fmaxf(x1, gx1[c]);
                float ly = fmaxf(y1, gy1[c]);
                float rx = fminf(x2, gx2[c]);
                float ry = fminf(y2, gy2[c]);
                float w  = fmaxf(rx - lx, 0.0f);
                float h  = fmaxf(ry - ly, 0.0f);
                float inter = w * h;
                float uni   = (pa + ga[c]) - inter;   // >= 1 (EPS forces dims >= 1)
                best[c] = fmaxf(best[c], inter * __builtin_amdgcn_rcpf(uni));
            }
        }
    } else {
        // intersection -> IoU: i/(2-i), monotone, 2-i in [1,2]
#pragma unroll
        for (int c = 0; c < COLS; ++c)
            best[c] = best[c] * __builtin_amdgcn_rcpf(2.0f - best[c]);
    }

    // ---- wave shuffle max-reduce, then cross-wave LDS combine ----
#pragma unroll
    for (int c = 0; c < COLS; ++c) {
#pragma unroll
        for (int off = 32; off >= 1; off >>= 1)
            best[c] = fmaxf(best[c], __shfl_xor(best[c], off, 64));
    }
    if (lane == 0) {
#pragma unroll
        for (int c = 0; c < COLS; ++c) swv[wv][c] = best[c];
    }
    __syncthreads();
    if (tid < COLS) {
        float m = swv[0][tid];
#pragma unroll
        for (int w = 1; w < WAVES; ++w) m = fmaxf(m, swv[w][tid]);
        int j = jb + tid;
        if (j < M) out[j] = 1.0f - m;
    }
}

extern "C" void kernel_launch(void* const* d_in, const int* in_sizes, int n_in,
                              void* d_out, int out_size, void* d_ws, size_t ws_size,
                              hipStream_t stream) {
    const float* pred = (const float*)d_in[0];
    const float* trub = (const float*)d_in[1];
    float* out = (float*)d_out;
    const int N = in_sizes[0] / 4;
    const int M = in_sizes[1] / 4;

    // one node: each block owns COLS disjoint outputs, scans all preds (L2-resident)
    int nblk = (M + COLS - 1) / COLS;   // 512 for M=8192
    iou_onepass<<<nblk, BLOCK, 0, stream>>>(pred, trub, out, N, M);
}